// Round 13
// baseline (212.009 us; speedup 1.0000x reference)
//
#include <hip/hip_runtime.h>
#include <hip/hip_cooperative_groups.h>

namespace cg = cooperative_groups;

constexpr int NN = 40000;
constexpr int NE = 640000;
constexpr int NBKT = 625;      // bucket = dst >> 6, 64 nodes per bucket; 625*64 == 40000
constexpr int PBLK = 256;      // fused-prep blocks; 256*2500 == NE, 256*5000 == NN*32

typedef __attribute__((ext_vector_type(8))) short short8;
typedef __attribute__((ext_vector_type(4))) float f32x4;
typedef __attribute__((ext_vector_type(2))) float f32x2;

// f32 -> bf16 round-to-nearest-even
__device__ __forceinline__ unsigned short rneb(float f) {
    unsigned u = __float_as_uint(f);
    u = (u + 0x7FFFu + ((u >> 16) & 1u)) >> 16;
    return (unsigned short)u;
}
__device__ __forceinline__ float b2f(unsigned short s) {
    return __uint_as_float(((unsigned)s) << 16);
}

// ---------------- fp8 e4m3 pack/unpack (HW cvt if available) ----------------
#if defined(__has_builtin)
#if __has_builtin(__builtin_amdgcn_cvt_pk_f32_fp8) && __has_builtin(__builtin_amdgcn_cvt_pk_fp8_f32)
#define FP8_HW 1
#endif
#endif

#ifndef FP8_HW
__device__ __forceinline__ unsigned char f32_to_fp8_sw(float f) {
    float a = fabsf(f);
    unsigned s = (f < 0.f) ? 0x80u : 0u;
    if (a > 448.f) a = 448.f;
    unsigned char r;
    if (a < 0.015625f) {
        int m = (int)rintf(a * 512.f);
        r = (m >= 8) ? (unsigned char)0x08 : (unsigned char)m;
    } else {
        unsigned u = __float_as_uint(a);
        u += 0x0007FFFFu + ((u >> 20) & 1u);
        int e8 = (int)((u >> 23) & 0xFF) - 127 + 7;
        unsigned m = (u >> 20) & 7u;
        if (e8 > 15 || (e8 == 15 && m == 7)) { e8 = 15; m = 6; }
        r = (unsigned char)((e8 << 3) | m);
    }
    return r | (unsigned char)s;
}
__device__ __forceinline__ float fp8_to_f32_sw(unsigned char b) {
    unsigned s = (b >> 7) & 1u, e = (b >> 3) & 0xFu, m = b & 7u;
    float v = e ? ldexpf((float)(8 + m), (int)e - 10) : ldexpf((float)m, -9);
    return s ? -v : v;
}
#endif

__device__ __forceinline__ unsigned pack_fp8x4(float4 v) {
#ifdef FP8_HW
    unsigned r = __builtin_amdgcn_cvt_pk_fp8_f32(v.x, v.y, 0, false);
    r = __builtin_amdgcn_cvt_pk_fp8_f32(v.z, v.w, (int)r, true);
    return r;
#else
    return (unsigned)f32_to_fp8_sw(v.x) | ((unsigned)f32_to_fp8_sw(v.y) << 8)
         | ((unsigned)f32_to_fp8_sw(v.z) << 16) | ((unsigned)f32_to_fp8_sw(v.w) << 24);
#endif
}

__device__ __forceinline__ void unpack_fp8x4(unsigned u, float* o) {
#ifdef FP8_HW
    f32x2 d0 = __builtin_amdgcn_cvt_pk_f32_fp8(u, false);
    f32x2 d1 = __builtin_amdgcn_cvt_pk_f32_fp8(u, true);
    o[0] = d0[0]; o[1] = d0[1]; o[2] = d1[0]; o[3] = d1[1];
#else
    o[0] = fp8_to_f32_sw((unsigned char)(u & 0xFF));
    o[1] = fp8_to_f32_sw((unsigned char)((u >> 8) & 0xFF));
    o[2] = fp8_to_f32_sw((unsigned char)((u >> 16) & 0xFF));
    o[3] = fp8_to_f32_sw((unsigned char)((u >> 24) & 0xFF));
#endif
}

// ---------- K1 (cooperative): cvtx(bf16+fp8) + cvtW + count -> scan -> scatter ----------
// Replaces 3 kernel launches (prep/cscan/cscatter) with one cooperative kernel:
// phase C's per-block LDS counts survive in LDS across grid.sync() and are
// reused by the scatter phase (no recount).
__global__ __launch_bounds__(1024) void fusedprep_k(const float* __restrict__ x,
                                                    unsigned short* __restrict__ xb,
                                                    unsigned* __restrict__ x8w,
                                                    const float* __restrict__ W,
                                                    unsigned short* __restrict__ Wb,
                                                    const int* __restrict__ dst,
                                                    const int* __restrict__ src,
                                                    const float* __restrict__ ew,
                                                    int* __restrict__ gcnt2,
                                                    int* __restrict__ bptr,
                                                    int* __restrict__ cursor,
                                                    unsigned* __restrict__ rec,
                                                    unsigned char* __restrict__ dloc) {
    cg::grid_group grid = cg::this_grid();
    __shared__ int cnt[NBKT];
    __shared__ int base[NBKT];
    __shared__ int sc[1024];
    int bid = blockIdx.x, t = threadIdx.x;

    // A: x f32 -> bf16 + fp8 (5000 f4-groups per block)
    int gb = bid * 5000;
    for (int i = t; i < 5000; i += 1024) {
        int g = gb + i;
        float4 v = reinterpret_cast<const float4*>(x)[g];
        ushort4 o = { rneb(v.x), rneb(v.y), rneb(v.z), rneb(v.w) };
        reinterpret_cast<ushort4*>(xb)[g] = o;
        x8w[g] = pack_fp8x4(v);
    }
    // B: W f32 -> bf16 (blocks 0..7)
    if (bid < 8) {
        int g = bid * 1024 + t;
        float4 v = reinterpret_cast<const float4*>(W)[g];
        ushort4 o = { rneb(v.x), rneb(v.y), rneb(v.z), rneb(v.w) };
        reinterpret_cast<ushort4*>(Wb)[g] = o;
    }
    // C: per-block bucket counts over its 2500 edges
    if (t < NBKT) cnt[t] = 0;
    __syncthreads();
    int eb = bid * 2500;
    for (int i = t; i < 2500; i += 1024)
        atomicAdd(&cnt[dst[eb + i] >> 6], 1);
    __syncthreads();
    if (t < NBKT) gcnt2[bid * 640 + t] = cnt[t];
    __threadfence();
    grid.sync();

    // D: block 0 scans the 625 bucket totals -> bptr, cursor
    if (bid == 0) {
        int c = 0;
        if (t < NBKT)
            for (int b = 0; b < PBLK; ++b) c += gcnt2[b * 640 + t];
        sc[t] = c;
        __syncthreads();
        for (int o = 1; o < 1024; o <<= 1) {
            int u = (t >= o) ? sc[t - o] : 0;
            __syncthreads();
            sc[t] += u;
            __syncthreads();
        }
        if (t < NBKT) {
            int excl = sc[t] - c;
            bptr[t]   = excl;
            cursor[t] = excl;
        }
        if (t == 0) bptr[NBKT] = NE;
        __threadfence();
    }
    grid.sync();

    // E: bucket scatter (reuses cnt[] kept in LDS from phase C)
    if (t < NBKT) {
        int c = cnt[t];
        base[t] = c ? atomicAdd(&cursor[t], c) : 0;
        cnt[t] = 0;                              // local cursor
    }
    __syncthreads();
    for (int i = t; i < 2500; i += 1024) {
        int d   = dst[eb + i];
        int bkt = d >> 6;
        int slot = atomicAdd(&cnt[bkt], 1);
        int p = base[bkt] + slot;
        unsigned short wh = __builtin_bit_cast(unsigned short, (_Float16)ew[eb + i]);
        rec[p]  = (unsigned)src[eb + i] | ((unsigned)wh << 16);
        dloc[p] = (unsigned char)(d & 63);
    }
}

// ---------- K2: fused aggregate + MFMA GEMM (EXACT R11 structure, proven 51.6us) ----------
__global__ __launch_bounds__(1024) void aggemm_k(const unsigned* __restrict__ rec,
                                                 const unsigned char* __restrict__ dloc,
                                                 const int* __restrict__ bptr,
                                                 const unsigned short* __restrict__ xb,
                                                 const unsigned char* __restrict__ x8,
                                                 const unsigned short* __restrict__ Wb,
                                                 const float* __restrict__ bias_p,
                                                 float* __restrict__ out) {
    constexpr int CAP = 2048;
    __shared__ unsigned grec[CAP];
    __shared__ int cnt[64];
    __shared__ int cur[64];
    __shared__ int pL[65];
    __shared__ unsigned short hbl[64 * 128];     // swizzled agg half, 16 KB
    int bkt = blockIdx.x, t = threadIdx.x;
    int beg = bptr[bkt], end = bptr[bkt + 1];
    int grp = t >> 4, fl = t & 15;               // 64 node-groups x 16 feature-lanes
    const uint2* xv = reinterpret_cast<const uint2*>(x8);   // row = 128B = 16 uint2
    float acc[8] = {0.f, 0.f, 0.f, 0.f, 0.f, 0.f, 0.f, 0.f};
    float wsv = 0.f;

    for (int cb = beg; cb < end; cb += CAP) {
        int m = end - cb; if (m > CAP) m = CAP;
        if (t < 64) cnt[t] = 0;
        __syncthreads();
        unsigned r0 = 0, r1 = 0; int d0 = -1, d1 = -1;
        if (t < m)        { r0 = rec[cb + t];        d0 = dloc[cb + t];        atomicAdd(&cnt[d0], 1); }
        if (t + 1024 < m) { r1 = rec[cb + t + 1024]; d1 = dloc[cb + t + 1024]; atomicAdd(&cnt[d1], 1); }
        __syncthreads();
        if (t < 64) {                            // wave 0: inclusive scan of 64 counts
            int v = cnt[t], s = v;
            #pragma unroll
            for (int o = 1; o < 64; o <<= 1) {
                int u = __shfl_up(s, o);
                if (t >= o) s += u;
            }
            pL[t]  = s - v;
            cur[t] = s - v;
            if (t == 63) pL[64] = s;
        }
        __syncthreads();
        if (d0 >= 0) { int p = atomicAdd(&cur[d0], 1); grec[p] = r0; }
        if (d1 >= 0) { int p = atomicAdd(&cur[d1], 1); grec[p] = r1; }
        __syncthreads();
        int gb = pL[grp], ge = pL[grp + 1];
        int e = gb;
        for (; e + 4 <= ge; e += 4) {            // unroll-4: 4 row-gathers in flight
            unsigned q0 = grec[e], q1 = grec[e + 1], q2 = grec[e + 2], q3 = grec[e + 3];
            uint2 a0 = xv[(size_t)(q0 & 0xFFFF) * 16 + fl];
            uint2 a1 = xv[(size_t)(q1 & 0xFFFF) * 16 + fl];
            uint2 a2 = xv[(size_t)(q2 & 0xFFFF) * 16 + fl];
            uint2 a3 = xv[(size_t)(q3 & 0xFFFF) * 16 + fl];
            float w0 = (float)__builtin_bit_cast(_Float16, (unsigned short)(q0 >> 16));
            float w1 = (float)__builtin_bit_cast(_Float16, (unsigned short)(q1 >> 16));
            float w2 = (float)__builtin_bit_cast(_Float16, (unsigned short)(q2 >> 16));
            float w3 = (float)__builtin_bit_cast(_Float16, (unsigned short)(q3 >> 16));
            wsv += w0 + w1 + w2 + w3;
            float f[8];
            unpack_fp8x4(a0.x, f); unpack_fp8x4(a0.y, f + 4);
            #pragma unroll
            for (int i = 0; i < 8; ++i) acc[i] += w0 * f[i];
            unpack_fp8x4(a1.x, f); unpack_fp8x4(a1.y, f + 4);
            #pragma unroll
            for (int i = 0; i < 8; ++i) acc[i] += w1 * f[i];
            unpack_fp8x4(a2.x, f); unpack_fp8x4(a2.y, f + 4);
            #pragma unroll
            for (int i = 0; i < 8; ++i) acc[i] += w2 * f[i];
            unpack_fp8x4(a3.x, f); unpack_fp8x4(a3.y, f + 4);
            #pragma unroll
            for (int i = 0; i < 8; ++i) acc[i] += w3 * f[i];
        }
        for (; e < ge; ++e) {                    // remainder (<=3)
            unsigned q = grec[e];
            uint2 a = xv[(size_t)(q & 0xFFFF) * 16 + fl];
            float w = (float)__builtin_bit_cast(_Float16, (unsigned short)(q >> 16));
            wsv += w;
            float f[8];
            unpack_fp8x4(a.x, f); unpack_fp8x4(a.y, f + 4);
            #pragma unroll
            for (int i = 0; i < 8; ++i) acc[i] += w * f[i];
        }
        __syncthreads();                         // protect grec/cnt for next chunk
    }

    {   // write node grp's agg slice (bf16) into swizzled LDS
        float inv = 1.f / fmaxf(wsv, 1e-8f);
        short8 o;
        #pragma unroll
        for (int i = 0; i < 8; ++i) o[i] = (short)rneb(acc[i] * inv);
        int gs = fl ^ (grp & 7);                 // granule swizzle
        *reinterpret_cast<short8*>(&hbl[grp * 128 + gs * 8]) = o;
    }
    __syncthreads();

    // ---- phase 2: MFMA ----
    int w = t >> 6, l = t & 63;
    int l15 = l & 15, lg = l >> 4;
    int rt = w & 3, ct0 = w >> 2;                // wave -> row-tile, col-tiles {ct0, ct0+4}
    f32x4 acc2[2] = { (f32x4)0.f, (f32x4)0.f };
    float bias2[2] = { bias_p[ct0 * 16 + l15], bias_p[(ct0 + 4) * 16 + l15] };
    int arow = bkt * 64 + rt * 16 + l15;

    #pragma unroll
    for (int step = 0; step < 8; ++step) {
        short8 a;
        if (step < 4) {
            a = *reinterpret_cast<const short8*>(xb + (size_t)arow * 128 + step * 32 + lg * 8);
        } else {
            int r = rt * 16 + l15;
            int g = (step - 4) * 4 + lg;         // granule 0..15 in agg half
            a = *reinterpret_cast<const short8*>(&hbl[r * 128 + (g ^ (r & 7)) * 8]);
        }
        #pragma unroll
        for (int q = 0; q < 2; ++q) {
            int ct = ct0 + q * 4;
            short8 bf = *reinterpret_cast<const short8*>(Wb + (size_t)(ct * 16 + l15) * 256 + step * 32 + lg * 8);
            acc2[q] = __builtin_amdgcn_mfma_f32_16x16x32_bf16(a, bf, acc2[q], 0, 0, 0);
        }
    }

    #pragma unroll
    for (int q = 0; q < 2; ++q)
        #pragma unroll
        for (int r4 = 0; r4 < 4; ++r4) {
            int row = bkt * 64 + rt * 16 + lg * 4 + r4;
            out[(size_t)row * 128 + (ct0 + q * 4) * 16 + l15] = acc2[q][r4] + bias2[q];
        }
}

// ==================== fallback path (small ws): atomic scatter + f32 GEMM ====================

__global__ void wsum_k(const int* __restrict__ dst, const float* __restrict__ ew,
                       float* __restrict__ wsum) {
    int e = blockIdx.x * 256 + threadIdx.x;
    if (e < NE) atomicAdd(&wsum[dst[e]], ew[e]);
}

__global__ void zerof_k(float* __restrict__ p, int n4) {
    int g = blockIdx.x * 256 + threadIdx.x;
    if (g < n4) reinterpret_cast<float4*>(p)[g] = make_float4(0.f, 0.f, 0.f, 0.f);
}

__global__ void scatter_k(const int* __restrict__ src, const int* __restrict__ dst,
                          const float* __restrict__ ew, const float* __restrict__ wsum,
                          const float* __restrict__ x, float* __restrict__ agg) {
    int tid = blockIdx.x * 256 + threadIdx.x;
    int e = tid >> 5;
    int p = tid & 31;
    if (e >= NE) return;
    int s = src[e], dn = dst[e];
    float wn = ew[e] / fmaxf(wsum[dn], 1e-8f);
    float4 v = *reinterpret_cast<const float4*>(x + (size_t)s * 128 + p * 4);
    float* o = agg + (size_t)dn * 128 + p * 4;
    atomicAdd(o + 0, wn * v.x);
    atomicAdd(o + 1, wn * v.y);
    atomicAdd(o + 2, wn * v.z);
    atomicAdd(o + 3, wn * v.w);
}

__global__ __launch_bounds__(256) void gemm_f32_k(const float* __restrict__ x,
                                                  const float* __restrict__ agg,
                                                  const float* __restrict__ W,
                                                  const float* __restrict__ b,
                                                  float* __restrict__ out) {
    __shared__ float4 Wl[128 * 64];
    __shared__ float4 hl[16 * 64];
    int t = threadIdx.x;
    int base = blockIdx.x * 80;
    const float4* Wg = reinterpret_cast<const float4*>(W);
    #pragma unroll
    for (int i = 0; i < 32; ++i) {
        int f = t + i * 256;
        int r = f >> 6, kk = f & 63;
        Wl[r * 64 + (kk ^ (r & 7))] = Wg[f];
    }
    int jj = t & 63, wsl = t >> 6, sw = jj & 7;
    float bv[2] = { b[jj], b[jj + 64] };
    const float4* xg = reinterpret_cast<const float4*>(x);
    const float4* ag = reinterpret_cast<const float4*>(agg);
    for (int g = 0; g < 5; ++g) {
        int nbase = base + g * 16;
        __syncthreads();
        #pragma unroll
        for (int i = 0; i < 4; ++i) {
            int f = t + i * 256;
            int ln = f >> 6, kk = f & 63;
            size_t node = (size_t)(nbase + ln);
            hl[ln * 64 + kk] = (kk < 32) ? xg[node * 32 + kk] : ag[node * 32 + (kk - 32)];
        }
        __syncthreads();
        float acc[2][4];
        #pragma unroll
        for (int q = 0; q < 2; ++q)
            #pragma unroll
            for (int n = 0; n < 4; ++n) acc[q][n] = 0.f;
        #pragma unroll 4
        for (int kk = 0; kk < 64; ++kk) {
            float4 h[4];
            #pragma unroll
            for (int n = 0; n < 4; ++n) h[n] = hl[(wsl + 4 * n) * 64 + kk];
            #pragma unroll
            for (int q = 0; q < 2; ++q) {
                float4 wvv = Wl[(jj + q * 64) * 64 + (kk ^ sw)];
                #pragma unroll
                for (int n = 0; n < 4; ++n)
                    acc[q][n] += wvv.x * h[n].x + wvv.y * h[n].y + wvv.z * h[n].z + wvv.w * h[n].w;
            }
        }
        #pragma unroll
        for (int q = 0; q < 2; ++q)
            #pragma unroll
            for (int n = 0; n < 4; ++n)
                out[(size_t)(nbase + wsl + 4 * n) * 128 + jj + q * 64] = acc[q][n] + bv[q];
    }
}

extern "C" void kernel_launch(void* const* d_in, const int* in_sizes, int n_in,
                              void* d_out, int out_size, void* d_ws, size_t ws_size,
                              hipStream_t stream) {
    const float* x  = (const float*)d_in[0];
    const int*   ei = (const int*)d_in[1];
    const float* ew = (const float*)d_in[2];
    const float* W  = (const float*)d_in[3];
    const float* b  = (const float*)d_in[4];
    float* out = (float*)d_out;
    const int* src = ei;
    const int* dst = ei + NE;

    // ws layout (bytes):
    //   0        : bptr [626 int]
    //   4096     : cursor [625 int]
    //   8192     : gcnt2 [256][640] int (655360) -> ends 663552
    //   665600   : Wb [128x256 bf16] (64 KB)
    //   733184   : dloc [640000 u8]
    //   1376256  : rec [640000 u32] (2.56 MB)
    //   4194304  : xb [40000][128] bf16 (10.24 MB)
    //   14434304 : x8 [40000][128] fp8 (5.12 MB) -> need ~19.6 MB (<23.4 proven)
    const size_t off_cursor = 4096;
    const size_t off_gcnt2  = 8192;
    const size_t off_Wb     = 665600;
    const size_t off_dloc   = 733184;
    const size_t off_rec    = 1376256;
    const size_t off_xb     = 4194304;
    const size_t off_x8     = 14434304;
    const size_t need = off_x8 + (size_t)NN * 128;

    if (ws_size >= need) {
        int* bptr   = (int*)d_ws;
        int* cursor = (int*)((char*)d_ws + off_cursor);
        int* gcnt2  = (int*)((char*)d_ws + off_gcnt2);
        unsigned short* Wb = (unsigned short*)((char*)d_ws + off_Wb);
        unsigned char* dloc = (unsigned char*)((char*)d_ws + off_dloc);
        unsigned* rec = (unsigned*)((char*)d_ws + off_rec);
        unsigned short* xb = (unsigned short*)((char*)d_ws + off_xb);
        unsigned char* x8 = (unsigned char*)((char*)d_ws + off_x8);
        unsigned* x8w = (unsigned*)x8;

        void* args[] = { (void*)&x, (void*)&xb, (void*)&x8w, (void*)&W, (void*)&Wb,
                         (void*)&dst, (void*)&src, (void*)&ew, (void*)&gcnt2,
                         (void*)&bptr, (void*)&cursor, (void*)&rec, (void*)&dloc };
        hipLaunchCooperativeKernel((const void*)fusedprep_k, dim3(PBLK), dim3(1024),
                                   args, 0, stream);
        aggemm_k<<<NBKT, 1024, 0, stream>>>(rec, dloc, bptr, xb, x8, Wb, b, out);
    } else {
        float* wsum = (float*)d_ws;
        float* agg  = out;
        zerof_k  <<<(NN / 4 + 255) / 256, 256, 0, stream>>>(wsum, NN / 4);
        zerof_k  <<<(NN * 32 + 255) / 256, 256, 0, stream>>>(agg, NN * 32);
        wsum_k   <<<(NE + 255) / 256, 256, 0, stream>>>(dst, ew, wsum);
        scatter_k<<<NE * 32 / 256, 256, 0, stream>>>(src, dst, ew, wsum, x, agg);
        gemm_f32_k<<<500, 256, 0, stream>>>(x, agg, W, b, out);
    }
}

// Round 14
// 83.899 us; speedup vs baseline: 2.5270x; 2.5270x over previous
//
#include <hip/hip_runtime.h>

constexpr int NN = 40000;
constexpr int NE = 640000;
constexpr int NBKT = 625;      // bucket = dst >> 6, 64 nodes per bucket; 625*64 == 40000
constexpr int CBLK = 128;      // count/scatter blocks; 128*5000 == NE

typedef __attribute__((ext_vector_type(8))) short short8;
typedef __attribute__((ext_vector_type(4))) float f32x4;
typedef __attribute__((ext_vector_type(2))) float f32x2;

// f32 -> bf16 round-to-nearest-even
__device__ __forceinline__ unsigned short rneb(float f) {
    unsigned u = __float_as_uint(f);
    u = (u + 0x7FFFu + ((u >> 16) & 1u)) >> 16;
    return (unsigned short)u;
}
__device__ __forceinline__ float b2f(unsigned short s) {
    return __uint_as_float(((unsigned)s) << 16);
}

// ---------------- fp8 e4m3 pack/unpack (HW cvt if available) ----------------
#if defined(__has_builtin)
#if __has_builtin(__builtin_amdgcn_cvt_pk_f32_fp8) && __has_builtin(__builtin_amdgcn_cvt_pk_fp8_f32)
#define FP8_HW 1
#endif
#endif

#ifndef FP8_HW
__device__ __forceinline__ unsigned char f32_to_fp8_sw(float f) {
    float a = fabsf(f);
    unsigned s = (f < 0.f) ? 0x80u : 0u;
    if (a > 448.f) a = 448.f;
    unsigned char r;
    if (a < 0.015625f) {
        int m = (int)rintf(a * 512.f);
        r = (m >= 8) ? (unsigned char)0x08 : (unsigned char)m;
    } else {
        unsigned u = __float_as_uint(a);
        u += 0x0007FFFFu + ((u >> 20) & 1u);
        int e8 = (int)((u >> 23) & 0xFF) - 127 + 7;
        unsigned m = (u >> 20) & 7u;
        if (e8 > 15 || (e8 == 15 && m == 7)) { e8 = 15; m = 6; }
        r = (unsigned char)((e8 << 3) | m);
    }
    return r | (unsigned char)s;
}
__device__ __forceinline__ float fp8_to_f32_sw(unsigned char b) {
    unsigned s = (b >> 7) & 1u, e = (b >> 3) & 0xFu, m = b & 7u;
    float v = e ? ldexpf((float)(8 + m), (int)e - 10) : ldexpf((float)m, -9);
    return s ? -v : v;
}
#endif

__device__ __forceinline__ unsigned pack_fp8x4(float4 v) {
#ifdef FP8_HW
    unsigned r = __builtin_amdgcn_cvt_pk_fp8_f32(v.x, v.y, 0, false);
    r = __builtin_amdgcn_cvt_pk_fp8_f32(v.z, v.w, (int)r, true);
    return r;
#else
    return (unsigned)f32_to_fp8_sw(v.x) | ((unsigned)f32_to_fp8_sw(v.y) << 8)
         | ((unsigned)f32_to_fp8_sw(v.z) << 16) | ((unsigned)f32_to_fp8_sw(v.w) << 24);
#endif
}

__device__ __forceinline__ void unpack_fp8x4(unsigned u, float* o) {
#ifdef FP8_HW
    f32x2 d0 = __builtin_amdgcn_cvt_pk_f32_fp8(u, false);
    f32x2 d1 = __builtin_amdgcn_cvt_pk_f32_fp8(u, true);
    o[0] = d0[0]; o[1] = d0[1]; o[2] = d1[0]; o[3] = d1[1];
#else
    o[0] = fp8_to_f32_sw((unsigned char)(u & 0xFF));
    o[1] = fp8_to_f32_sw((unsigned char)((u >> 8) & 0xFF));
    o[2] = fp8_to_f32_sw((unsigned char)((u >> 16) & 0xFF));
    o[3] = fp8_to_f32_sw((unsigned char)((u >> 24) & 0xFF));
#endif
}

// ---------- K1: fused cvtx(bf16 + fp8) + cvtW + per-block bucket counts (R11) ----------
__global__ __launch_bounds__(1024) void prep_k(const float* __restrict__ x,
                                               unsigned short* __restrict__ xb,
                                               unsigned* __restrict__ x8w,
                                               const float* __restrict__ W,
                                               unsigned short* __restrict__ Wb,
                                               const int* __restrict__ dst,
                                               int* __restrict__ gcnt2) {
    __shared__ int cnt[NBKT];
    int bid = blockIdx.x, t = threadIdx.x;
    if (bid < 1250) {                            // x: 1250*1024 == NN*32 f4-groups
        int g = bid * 1024 + t;
        float4 v = reinterpret_cast<const float4*>(x)[g];
        ushort4 o = { rneb(v.x), rneb(v.y), rneb(v.z), rneb(v.w) };
        reinterpret_cast<ushort4*>(xb)[g] = o;
        x8w[g] = pack_fp8x4(v);                  // fp8 copy for the gather
    } else if (bid < 1258) {                     // W: 8*1024 == 128*256/4 f4-groups
        int g = (bid - 1250) * 1024 + t;
        float4 v = reinterpret_cast<const float4*>(W)[g];
        ushort4 o = { rneb(v.x), rneb(v.y), rneb(v.z), rneb(v.w) };
        reinterpret_cast<ushort4*>(Wb)[g] = o;
    } else {                                     // counts: 128 blocks x 5000 edges
        int cb = bid - 1258;
        if (t < NBKT) cnt[t] = 0;
        __syncthreads();
        int eb = cb * 5000;
        for (int i = t; i < 5000; i += 1024)
            atomicAdd(&cnt[dst[eb + i] >> 6], 1);
        __syncthreads();
        if (t < NBKT) gcnt2[cb * 640 + t] = cnt[t];
    }
}

// ---------- K2: merged scan + scatter ----------
// Each of the 128 blocks redundantly computes the global bucket scan from
// gcnt2 (L2-hot after block 0) plus its own deterministic per-bucket base
// (bucket_base + counts of earlier blocks) -- no cursor atomics, one launch
// fewer than R11. Block 0 writes bptr for aggemm.
__global__ __launch_bounds__(1024) void scanscatter_k(const int* __restrict__ dst,
                                                      const int* __restrict__ src,
                                                      const float* __restrict__ ew,
                                                      const int* __restrict__ gcnt2,
                                                      int* __restrict__ bptr,
                                                      unsigned* __restrict__ rec,
                                                      unsigned char* __restrict__ dloc) {
    __shared__ int sc[1024];
    __shared__ int base[NBKT];
    __shared__ int cnt[NBKT];
    int t = threadIdx.x, cb = blockIdx.x;
    int ctot = 0, cpre = 0;
    if (t < NBKT) {
        for (int b = 0; b < CBLK; ++b) {
            int v = gcnt2[b * 640 + t];
            cpre += (b < cb) ? v : 0;
            ctot += v;
        }
    }
    sc[t] = (t < NBKT) ? ctot : 0;
    __syncthreads();
    for (int o = 1; o < 1024; o <<= 1) {
        int u = (t >= o) ? sc[t - o] : 0;
        __syncthreads();
        sc[t] += u;
        __syncthreads();
    }
    if (t < NBKT) {
        int excl = sc[t] - ctot;                 // global bucket base
        base[t] = excl + cpre;                   // this block's run start
        cnt[t] = 0;                              // local cursor
        if (cb == 0) bptr[t] = excl;
    }
    if (cb == 0 && t == 0) bptr[NBKT] = NE;
    __syncthreads();
    int eb = cb * 5000;
    for (int i = t; i < 5000; i += 1024) {
        int d   = dst[eb + i];
        int bkt = d >> 6;
        int slot = atomicAdd(&cnt[bkt], 1);
        int p = base[bkt] + slot;
        unsigned short wh = __builtin_bit_cast(unsigned short, (_Float16)ew[eb + i]);
        rec[p]  = (unsigned)src[eb + i] | ((unsigned)wh << 16);
        dloc[p] = (unsigned char)(d & 63);
    }
}

// ---------- K3: fused aggregate + MFMA GEMM (EXACT R11 structure, proven 51.6us) ----------
__global__ __launch_bounds__(1024) void aggemm_k(const unsigned* __restrict__ rec,
                                                 const unsigned char* __restrict__ dloc,
                                                 const int* __restrict__ bptr,
                                                 const unsigned short* __restrict__ xb,
                                                 const unsigned char* __restrict__ x8,
                                                 const unsigned short* __restrict__ Wb,
                                                 const float* __restrict__ bias_p,
                                                 float* __restrict__ out) {
    constexpr int CAP = 2048;
    __shared__ unsigned grec[CAP];
    __shared__ int cnt[64];
    __shared__ int cur[64];
    __shared__ int pL[65];
    __shared__ unsigned short hbl[64 * 128];     // swizzled agg half, 16 KB
    int bkt = blockIdx.x, t = threadIdx.x;
    int beg = bptr[bkt], end = bptr[bkt + 1];
    int grp = t >> 4, fl = t & 15;               // 64 node-groups x 16 feature-lanes
    const uint2* xv = reinterpret_cast<const uint2*>(x8);   // row = 128B = 16 uint2
    float acc[8] = {0.f, 0.f, 0.f, 0.f, 0.f, 0.f, 0.f, 0.f};
    float wsv = 0.f;

    for (int cb = beg; cb < end; cb += CAP) {
        int m = end - cb; if (m > CAP) m = CAP;
        if (t < 64) cnt[t] = 0;
        __syncthreads();
        unsigned r0 = 0, r1 = 0; int d0 = -1, d1 = -1;
        if (t < m)        { r0 = rec[cb + t];        d0 = dloc[cb + t];        atomicAdd(&cnt[d0], 1); }
        if (t + 1024 < m) { r1 = rec[cb + t + 1024]; d1 = dloc[cb + t + 1024]; atomicAdd(&cnt[d1], 1); }
        __syncthreads();
        if (t < 64) {                            // wave 0: inclusive scan of 64 counts
            int v = cnt[t], s = v;
            #pragma unroll
            for (int o = 1; o < 64; o <<= 1) {
                int u = __shfl_up(s, o);
                if (t >= o) s += u;
            }
            pL[t]  = s - v;
            cur[t] = s - v;
            if (t == 63) pL[64] = s;
        }
        __syncthreads();
        if (d0 >= 0) { int p = atomicAdd(&cur[d0], 1); grec[p] = r0; }
        if (d1 >= 0) { int p = atomicAdd(&cur[d1], 1); grec[p] = r1; }
        __syncthreads();
        int gb = pL[grp], ge = pL[grp + 1];
        int e = gb;
        for (; e + 4 <= ge; e += 4) {            // unroll-4: 4 row-gathers in flight
            unsigned q0 = grec[e], q1 = grec[e + 1], q2 = grec[e + 2], q3 = grec[e + 3];
            uint2 a0 = xv[(size_t)(q0 & 0xFFFF) * 16 + fl];
            uint2 a1 = xv[(size_t)(q1 & 0xFFFF) * 16 + fl];
            uint2 a2 = xv[(size_t)(q2 & 0xFFFF) * 16 + fl];
            uint2 a3 = xv[(size_t)(q3 & 0xFFFF) * 16 + fl];
            float w0 = (float)__builtin_bit_cast(_Float16, (unsigned short)(q0 >> 16));
            float w1 = (float)__builtin_bit_cast(_Float16, (unsigned short)(q1 >> 16));
            float w2 = (float)__builtin_bit_cast(_Float16, (unsigned short)(q2 >> 16));
            float w3 = (float)__builtin_bit_cast(_Float16, (unsigned short)(q3 >> 16));
            wsv += w0 + w1 + w2 + w3;
            float f[8];
            unpack_fp8x4(a0.x, f); unpack_fp8x4(a0.y, f + 4);
            #pragma unroll
            for (int i = 0; i < 8; ++i) acc[i] += w0 * f[i];
            unpack_fp8x4(a1.x, f); unpack_fp8x4(a1.y, f + 4);
            #pragma unroll
            for (int i = 0; i < 8; ++i) acc[i] += w1 * f[i];
            unpack_fp8x4(a2.x, f); unpack_fp8x4(a2.y, f + 4);
            #pragma unroll
            for (int i = 0; i < 8; ++i) acc[i] += w2 * f[i];
            unpack_fp8x4(a3.x, f); unpack_fp8x4(a3.y, f + 4);
            #pragma unroll
            for (int i = 0; i < 8; ++i) acc[i] += w3 * f[i];
        }
        for (; e < ge; ++e) {                    // remainder (<=3)
            unsigned q = grec[e];
            uint2 a = xv[(size_t)(q & 0xFFFF) * 16 + fl];
            float w = (float)__builtin_bit_cast(_Float16, (unsigned short)(q >> 16));
            wsv += w;
            float f[8];
            unpack_fp8x4(a.x, f); unpack_fp8x4(a.y, f + 4);
            #pragma unroll
            for (int i = 0; i < 8; ++i) acc[i] += w * f[i];
        }
        __syncthreads();                         // protect grec/cnt for next chunk
    }

    {   // write node grp's agg slice (bf16) into swizzled LDS
        float inv = 1.f / fmaxf(wsv, 1e-8f);
        short8 o;
        #pragma unroll
        for (int i = 0; i < 8; ++i) o[i] = (short)rneb(acc[i] * inv);
        int gs = fl ^ (grp & 7);                 // granule swizzle
        *reinterpret_cast<short8*>(&hbl[grp * 128 + gs * 8]) = o;
    }
    __syncthreads();

    // ---- phase 2: MFMA ----
    int w = t >> 6, l = t & 63;
    int l15 = l & 15, lg = l >> 4;
    int rt = w & 3, ct0 = w >> 2;                // wave -> row-tile, col-tiles {ct0, ct0+4}
    f32x4 acc2[2] = { (f32x4)0.f, (f32x4)0.f };
    float bias2[2] = { bias_p[ct0 * 16 + l15], bias_p[(ct0 + 4) * 16 + l15] };
    int arow = bkt * 64 + rt * 16 + l15;

    #pragma unroll
    for (int step = 0; step < 8; ++step) {
        short8 a;
        if (step < 4) {
            a = *reinterpret_cast<const short8*>(xb + (size_t)arow * 128 + step * 32 + lg * 8);
        } else {
            int r = rt * 16 + l15;
            int g = (step - 4) * 4 + lg;         // granule 0..15 in agg half
            a = *reinterpret_cast<const short8*>(&hbl[r * 128 + (g ^ (r & 7)) * 8]);
        }
        #pragma unroll
        for (int q = 0; q < 2; ++q) {
            int ct = ct0 + q * 4;
            short8 bf = *reinterpret_cast<const short8*>(Wb + (size_t)(ct * 16 + l15) * 256 + step * 32 + lg * 8);
            acc2[q] = __builtin_amdgcn_mfma_f32_16x16x32_bf16(a, bf, acc2[q], 0, 0, 0);
        }
    }

    #pragma unroll
    for (int q = 0; q < 2; ++q)
        #pragma unroll
        for (int r4 = 0; r4 < 4; ++r4) {
            int row = bkt * 64 + rt * 16 + lg * 4 + r4;
            out[(size_t)row * 128 + (ct0 + q * 4) * 16 + l15] = acc2[q][r4] + bias2[q];
        }
}

// ==================== fallback path (small ws): atomic scatter + f32 GEMM ====================

__global__ void wsum_k(const int* __restrict__ dst, const float* __restrict__ ew,
                       float* __restrict__ wsum) {
    int e = blockIdx.x * 256 + threadIdx.x;
    if (e < NE) atomicAdd(&wsum[dst[e]], ew[e]);
}

__global__ void zerof_k(float* __restrict__ p, int n4) {
    int g = blockIdx.x * 256 + threadIdx.x;
    if (g < n4) reinterpret_cast<float4*>(p)[g] = make_float4(0.f, 0.f, 0.f, 0.f);
}

__global__ void scatter_k(const int* __restrict__ src, const int* __restrict__ dst,
                          const float* __restrict__ ew, const float* __restrict__ wsum,
                          const float* __restrict__ x, float* __restrict__ agg) {
    int tid = blockIdx.x * 256 + threadIdx.x;
    int e = tid >> 5;
    int p = tid & 31;
    if (e >= NE) return;
    int s = src[e], dn = dst[e];
    float wn = ew[e] / fmaxf(wsum[dn], 1e-8f);
    float4 v = *reinterpret_cast<const float4*>(x + (size_t)s * 128 + p * 4);
    float* o = agg + (size_t)dn * 128 + p * 4;
    atomicAdd(o + 0, wn * v.x);
    atomicAdd(o + 1, wn * v.y);
    atomicAdd(o + 2, wn * v.z);
    atomicAdd(o + 3, wn * v.w);
}

__global__ __launch_bounds__(256) void gemm_f32_k(const float* __restrict__ x,
                                                  const float* __restrict__ agg,
                                                  const float* __restrict__ W,
                                                  const float* __restrict__ b,
                                                  float* __restrict__ out) {
    __shared__ float4 Wl[128 * 64];
    __shared__ float4 hl[16 * 64];
    int t = threadIdx.x;
    int base = blockIdx.x * 80;
    const float4* Wg = reinterpret_cast<const float4*>(W);
    #pragma unroll
    for (int i = 0; i < 32; ++i) {
        int f = t + i * 256;
        int r = f >> 6, kk = f & 63;
        Wl[r * 64 + (kk ^ (r & 7))] = Wg[f];
    }
    int jj = t & 63, wsl = t >> 6, sw = jj & 7;
    float bv[2] = { b[jj], b[jj + 64] };
    const float4* xg = reinterpret_cast<const float4*>(x);
    const float4* ag = reinterpret_cast<const float4*>(agg);
    for (int g = 0; g < 5; ++g) {
        int nbase = base + g * 16;
        __syncthreads();
        #pragma unroll
        for (int i = 0; i < 4; ++i) {
            int f = t + i * 256;
            int ln = f >> 6, kk = f & 63;
            size_t node = (size_t)(nbase + ln);
            hl[ln * 64 + kk] = (kk < 32) ? xg[node * 32 + kk] : ag[node * 32 + (kk - 32)];
        }
        __syncthreads();
        float acc[2][4];
        #pragma unroll
        for (int q = 0; q < 2; ++q)
            #pragma unroll
            for (int n = 0; n < 4; ++n) acc[q][n] = 0.f;
        #pragma unroll 4
        for (int kk = 0; kk < 64; ++kk) {
            float4 h[4];
            #pragma unroll
            for (int n = 0; n < 4; ++n) h[n] = hl[(wsl + 4 * n) * 64 + kk];
            #pragma unroll
            for (int q = 0; q < 2; ++q) {
                float4 wvv = Wl[(jj + q * 64) * 64 + (kk ^ sw)];
                #pragma unroll
                for (int n = 0; n < 4; ++n)
                    acc[q][n] += wvv.x * h[n].x + wvv.y * h[n].y + wvv.z * h[n].z + wvv.w * h[n].w;
            }
        }
        #pragma unroll
        for (int q = 0; q < 2; ++q)
            #pragma unroll
            for (int n = 0; n < 4; ++n)
                out[(size_t)(nbase + wsl + 4 * n) * 128 + jj + q * 64] = acc[q][n] + bv[q];
    }
}

extern "C" void kernel_launch(void* const* d_in, const int* in_sizes, int n_in,
                              void* d_out, int out_size, void* d_ws, size_t ws_size,
                              hipStream_t stream) {
    const float* x  = (const float*)d_in[0];
    const int*   ei = (const int*)d_in[1];
    const float* ew = (const float*)d_in[2];
    const float* W  = (const float*)d_in[3];
    const float* b  = (const float*)d_in[4];
    float* out = (float*)d_out;
    const int* src = ei;
    const int* dst = ei + NE;

    // ws layout (bytes) -- same as R11:
    //   0        : bptr [626 int]
    //   8192     : gcnt2 [128][640] int (327680) -> ends 335872
    //   339968   : Wb [128x256 bf16] (64 KB)
    //   405504   : dloc [640000 u8]
    //   1048576  : rec [640000 u32] (2.56 MB)
    //   3670016  : xb [40000][128] bf16 (10.24 MB)
    //   13910016 : x8 [40000][128] fp8 (5.12 MB) -> need ~18.2 MB (proven R11)
    const size_t off_gcnt2  = 8192;
    const size_t off_Wb     = 339968;
    const size_t off_dloc   = 405504;
    const size_t off_rec    = 1048576;
    const size_t off_xb     = 3670016;
    const size_t off_x8     = 13910016;
    const size_t need = off_x8 + (size_t)NN * 128;

    if (ws_size >= need) {
        int* bptr   = (int*)d_ws;
        int* gcnt2  = (int*)((char*)d_ws + off_gcnt2);
        unsigned short* Wb = (unsigned short*)((char*)d_ws + off_Wb);
        unsigned char* dloc = (unsigned char*)((char*)d_ws + off_dloc);
        unsigned* rec = (unsigned*)((char*)d_ws + off_rec);
        unsigned short* xb = (unsigned short*)((char*)d_ws + off_xb);
        unsigned char* x8 = (unsigned char*)((char*)d_ws + off_x8);

        prep_k       <<<1386, 1024, 0, stream>>>(x, xb, (unsigned*)x8, W, Wb, dst, gcnt2);
        scanscatter_k<<<CBLK, 1024, 0, stream>>>(dst, src, ew, gcnt2, bptr, rec, dloc);
        aggemm_k     <<<NBKT, 1024, 0, stream>>>(rec, dloc, bptr, xb, x8, Wb, b, out);
    } else {
        float* wsum = (float*)d_ws;
        float* agg  = out;
        zerof_k  <<<(NN / 4 + 255) / 256, 256, 0, stream>>>(wsum, NN / 4);
        zerof_k  <<<(NN * 32 + 255) / 256, 256, 0, stream>>>(agg, NN * 32);
        wsum_k   <<<(NE + 255) / 256, 256, 0, stream>>>(dst, ew, wsum);
        scatter_k<<<NE * 32 / 256, 256, 0, stream>>>(src, dst, ew, wsum, x, agg);
        gemm_f32_k<<<500, 256, 0, stream>>>(x, agg, W, b, out);
    }
}